// Round 9
// baseline (626.582 us; speedup 1.0000x reference)
//
#include <hip/hip_runtime.h>
#include <hip/hip_bf16.h>

#define BB 4
#define SS 1024
#define HH 1024
#define NHH 16
#define DD 64
#define MAXPOS 1024

typedef __hip_bfloat16 bf16;
typedef unsigned short ushort_t;
typedef __attribute__((ext_vector_type(8))) short short8;
typedef __attribute__((ext_vector_type(4))) float f32x4;
typedef __attribute__((ext_vector_type(4))) unsigned short us4;

#define MFMA_16x16x32(a, b, c) __builtin_amdgcn_mfma_f32_16x16x32_bf16((a), (b), (c), 0, 0, 0)

__device__ __forceinline__ float bu2f(ushort_t u) {
    union { unsigned int i; float f; } c; c.i = ((unsigned int)u) << 16; return c.f;
}
__device__ __forceinline__ ushort_t f2bu(float f) {
    __hip_bfloat16 h = __float2bfloat16(f);
    return *reinterpret_cast<ushort_t*>(&h);
}
// packed 2xfp32 -> 2xbf16 (v_cvt_pk_bf16_f32), low half = first arg
__device__ __forceinline__ unsigned int pkbf(float a, float b) {
    __hip_bfloat162 h = __float22bfloat162_rn(make_float2(a, b));
    union { __hip_bfloat162 h2; unsigned int u; } c; c.h2 = h;
    return c.u;
}

// ---------------------------------------------------------------------------
// Kernel 0: all fp32->bf16 conversions in one launch (x, 4 weights, E).
// ---------------------------------------------------------------------------
__global__ void conv_all(const float* __restrict__ x,  const float* __restrict__ Wq,
                         const float* __restrict__ Wk, const float* __restrict__ Wv,
                         const float* __restrict__ Wo, const float* __restrict__ dist,
                         ushort_t* __restrict__ xb,  ushort_t* __restrict__ Wqb,
                         ushort_t* __restrict__ Wkb, ushort_t* __restrict__ Wvb,
                         ushort_t* __restrict__ Wob, ushort_t* __restrict__ Eb)
{
    const int i = blockIdx.x * 256 + threadIdx.x;
    const float* src; ushort_t* dst; int off;
    if (i < 1048576)      { src = x;  dst = xb;  off = i; }
    else if (i < 1310720) { src = Wq; dst = Wqb; off = i - 1048576; }
    else if (i < 1572864) { src = Wk; dst = Wkb; off = i - 1310720; }
    else if (i < 1835008) { src = Wv; dst = Wvb; off = i - 1572864; }
    else if (i < 2097152) { src = Wo; dst = Wob; off = i - 1835008; }
    else if (i < 2129920) {
        const int j = i - 2097152;
        float4 f = (j < 32752) ? ((const float4*)dist)[j] : make_float4(0.f, 0.f, 0.f, 0.f);
        ((uint2*)Eb)[j] = make_uint2(pkbf(f.x, f.y), pkbf(f.z, f.w));
        return;
    } else return;
    float4 f = ((const float4*)src)[off];
    ((uint2*)dst)[off] = make_uint2(pkbf(f.x, f.y), pkbf(f.z, f.w));
}

// ---------------------------------------------------------------------------
// Kernel 1: QKV projection, MFMA.  C = xb @ W^T (+bias).
//   Q -> [B,NH,S,D] pre-scaled 0.125;  K -> [B,NH,S,D];  V -> [B,NH,D,S].
// For Q/K the MFMA operands are SWAPPED (C^T layout) so the g-index runs
// along d -> packed uint2 epilogue stores.  V uses original order (g runs
// along l, packed stores into the transposed [d][s] layout).
// grid (8, 32, 3), block 256 (4 waves, 2x2 of 64x64).
// ---------------------------------------------------------------------------
__global__ __launch_bounds__(256)
void qkv_mfma(const ushort_t* __restrict__ xb,
              const ushort_t* __restrict__ Wqb, const float* __restrict__ bq,
              const ushort_t* __restrict__ Wkb, const float* __restrict__ bk,
              const ushort_t* __restrict__ Wvb, const float* __restrict__ bv,
              ushort_t* __restrict__ q, ushort_t* __restrict__ k,
              ushort_t* __restrict__ vt)
{
    const int which = blockIdx.z;
    const ushort_t* __restrict__ W    = (which == 0) ? Wqb : (which == 1) ? Wkb : Wvb;
    const float*    __restrict__ bias = (which == 0) ? bq  : (which == 1) ? bk  : bv;

    const int tid = threadIdx.x, w = tid >> 6, lane = tid & 63;
    const int quad = lane >> 4, lq = lane & 15;
    const int wm = w >> 1, wn = w & 1;
    const int m0 = blockIdx.y * 128 + wm * 64;
    const int n0 = blockIdx.x * 128 + wn * 64;

    f32x4 acc[4][4];
#pragma unroll
    for (int i = 0; i < 4; i++)
#pragma unroll
        for (int j = 0; j < 4; j++) acc[i][j] = (f32x4){0.f, 0.f, 0.f, 0.f};

    const ushort_t* aB = xb + (size_t)(m0 + lq) * 1024 + quad * 8;
    const ushort_t* bB = W  + (size_t)(n0 + lq) * 1024 + quad * 8;

    if (which == 2) {
#pragma unroll 2
        for (int k0 = 0; k0 < 1024; k0 += 32) {
            short8 af[4], bf[4];
#pragma unroll
            for (int i = 0; i < 4; i++) af[i] = *(const short8*)(aB + i * 16 * 1024 + k0);
#pragma unroll
            for (int j = 0; j < 4; j++) bf[j] = *(const short8*)(bB + j * 16 * 1024 + k0);
#pragma unroll
            for (int i = 0; i < 4; i++)
#pragma unroll
                for (int j = 0; j < 4; j++)
                    acc[i][j] = MFMA_16x16x32(af[i], bf[j], acc[i][j]);
        }
        // V^T epilogue: lane holds (m = quad*4+g contiguous l, n = lq -> d)
#pragma unroll
        for (int j = 0; j < 4; j++) {
            const int n  = n0 + j * 16 + lq;
            const int h_ = n >> 6, d_ = n & 63;
            const float bb = bias[n];
#pragma unroll
            for (int i = 0; i < 4; i++) {
                const int m  = m0 + i * 16 + quad * 4;
                const int b_ = m >> 10, l = m & 1023;
                uint2 pv = make_uint2(pkbf(acc[i][j][0] + bb, acc[i][j][1] + bb),
                                      pkbf(acc[i][j][2] + bb, acc[i][j][3] + bb));
                *(uint2*)(vt + (((size_t)(b_ * NHH) + h_) * DD + d_) * SS + l) = pv;
            }
        }
    } else {
        // swapped operands: C^T layout, lane holds (n = quad*4+g -> d, m = lq -> l)
#pragma unroll 2
        for (int k0 = 0; k0 < 1024; k0 += 32) {
            short8 af[4], bf[4];
#pragma unroll
            for (int i = 0; i < 4; i++) af[i] = *(const short8*)(aB + i * 16 * 1024 + k0);
#pragma unroll
            for (int j = 0; j < 4; j++) bf[j] = *(const short8*)(bB + j * 16 * 1024 + k0);
#pragma unroll
            for (int i = 0; i < 4; i++)
#pragma unroll
                for (int j = 0; j < 4; j++)
                    acc[i][j] = MFMA_16x16x32(bf[j], af[i], acc[i][j]);
        }
        ushort_t* __restrict__ out = (which == 0) ? q : k;
        const float sc = (which == 0) ? 0.125f : 1.0f;
#pragma unroll
        for (int j = 0; j < 4; j++) {
            const int nn = n0 + j * 16 + quad * 4;   // g=0 col
            const int h_ = nn >> 6, d0 = nn & 63;
            float bs[4];
#pragma unroll
            for (int g = 0; g < 4; g++) bs[g] = bias[nn + g];
#pragma unroll
            for (int i = 0; i < 4; i++) {
                const int m  = m0 + i * 16 + lq;
                const int b_ = m >> 10, l = m & 1023;
                float s0 = (acc[i][j][0] + bs[0]) * sc;
                float s1 = (acc[i][j][1] + bs[1]) * sc;
                float s2 = (acc[i][j][2] + bs[2]) * sc;
                float s3 = (acc[i][j][3] + bs[3]) * sc;
                *(uint2*)(out + (((size_t)(b_ * NHH) + h_) * SS + l) * DD + d0) =
                    make_uint2(pkbf(s0, s1), pkbf(s2, s3));
            }
        }
    }
}

// ---------------------------------------------------------------------------
// Kernel 2: MFMA flash attention, S^T formulation.
// LDS = QEsT + KEsT only (34,816 B -> 4 wg/CU); PsT aliases the head of
// QEsT, protected by a 3rd barrier (P is written only after all score-phase
// LDS reads complete; next tile's QE stores wait on the loop-top barrier).
// grid (16, 16, 4), block 256, 4 waves/EU.
// ---------------------------------------------------------------------------
__global__ __launch_bounds__(256, 4)
void attn_mfma(const ushort_t* __restrict__ qb, const ushort_t* __restrict__ kb,
               const ushort_t* __restrict__ vt, const ushort_t* __restrict__ Eb,
               const float* __restrict__ mask, ushort_t* __restrict__ ctx)
{
    const int l0 = blockIdx.x * 64;
    const int h  = blockIdx.y, b = blockIdx.z;
    const int tid  = threadIdx.x;
    const int w    = tid >> 6;
    const int lane = tid & 63;
    const int quad = lane >> 4, lq = lane & 15;

    __shared__ __align__(16) ushort_t QEsT[128 * 68];   // [t][l]
    __shared__ __align__(16) ushort_t KEsT[128 * 68];   // [t][r]
    ushort_t* const PsT = QEsT;                         // [l][r] stride 72, 9216 B alias

    const ushort_t* qbh = qb + (size_t)(b * NHH + h) * SS * DD;
    const ushort_t* kbh = kb + (size_t)(b * NHH + h) * SS * DD;
    const ushort_t* vth = vt + (size_t)(b * NHH + h) * DD * SS;   // [d][s]

    short8 qa0, qa1;
    {
        const ushort_t* p = qbh + (l0 + w * 16 + lq) * DD + quad * 8;
        qa0 = *(const short8*)p;
        qa1 = *(const short8*)(p + 32);
    }
    const int l_loc = w * 16 + lq;

    f32x4 Oacc[4];
#pragma unroll
    for (int dt = 0; dt < 4; dt++) Oacc[dt] = (f32x4){0.f, 0.f, 0.f, 0.f};
    float mrow = -3e38f, lrow = 0.f;

    for (int rt = 0; rt < 16; rt++) {
        const int r0   = rt * 64;
        const int dmin = l0 - r0 + 960;

        short8 kf0[4], kf1[4];
#pragma unroll
        for (int ct = 0; ct < 4; ct++) {
            const ushort_t* p = kbh + (r0 + ct * 16 + lq) * DD + quad * 8;
            kf0[ct] = *(const short8*)p;
            kf1[ct] = *(const short8*)(p + 32);
        }
        float mk[4];
#pragma unroll
        for (int g = 0; g < 4; g++) mk[g] = mask[b * SS + r0 + w * 16 + quad * 4 + g];

        __syncthreads();   // (1) prior tile: score reads + PV reads of PsT alias done

        // --- QE / KE' via MFMA, transposed packed stores ---
#pragma unroll
        for (int tt = 0; tt < 8; tt++) {
            const ushort_t* ep = Eb + (size_t)(dmin + tt * 16 + lq) * DD + quad * 8;
            short8 e0 = *(const short8*)ep;
            short8 e1 = *(const short8*)(ep + 32);
            f32x4 qe = (f32x4){0.f, 0.f, 0.f, 0.f};
            f32x4 ke = (f32x4){0.f, 0.f, 0.f, 0.f};
            qe = MFMA_16x16x32(qa0, e0, qe);
            qe = MFMA_16x16x32(qa1, e1, qe);
            ke = MFMA_16x16x32(kf0[w], e0, ke);
            ke = MFMA_16x16x32(kf1[w], e1, ke);
            const float k0 = ke[0] * 0.125f + mk[0];
            const float k1 = ke[1] * 0.125f + mk[1];
            const float k2 = ke[2] * 0.125f + mk[2];
            const float k3 = ke[3] * 0.125f + mk[3];
            const int trow = tt * 16 + lq;
            *(uint2*)&QEsT[trow * 68 + w * 16 + quad * 4] =
                make_uint2(pkbf(qe[0], qe[1]), pkbf(qe[2], qe[3]));
            *(uint2*)&KEsT[trow * 68 + w * 16 + quad * 4] =
                make_uint2(pkbf(k0, k1), pkbf(k2, k3));
        }

        // --- S^T = K Q^T for this wave's l-block ---
        f32x4 st[4];
#pragma unroll
        for (int ct = 0; ct < 4; ct++) {
            f32x4 a = (f32x4){0.f, 0.f, 0.f, 0.f};
            a = MFMA_16x16x32(kf0[ct], qa0, a);
            a = MFMA_16x16x32(kf1[ct], qa1, a);
            st[ct] = a;
        }

        __syncthreads();   // (2) QEsT/KEsT visible

        // --- scores + online softmax (per-lane l fixed) ---
        float p[4][4];
        float tmax = -3e38f;
#pragma unroll
        for (int ct = 0; ct < 4; ct++) {
#pragma unroll
            for (int g = 0; g < 4; g++) {
                const int r_loc = ct * 16 + quad * 4 + g;
                const int t = l_loc - r_loc + 63;      // [0,126]
                float s = st[ct][g] + bu2f(QEsT[t * 68 + l_loc])
                                    + bu2f(KEsT[t * 68 + r_loc]);
                p[ct][g] = s;
                tmax = fmaxf(tmax, s);
            }
        }
        tmax = fmaxf(tmax, __shfl_xor(tmax, 16));
        tmax = fmaxf(tmax, __shfl_xor(tmax, 32));
        const float mnew  = fmaxf(mrow, tmax);
        const float alpha = __expf(mrow - mnew);
        mrow = mnew;
        float psum = 0.f;
#pragma unroll
        for (int ct = 0; ct < 4; ct++)
#pragma unroll
            for (int g = 0; g < 4; g++) {
                const float e = __expf(p[ct][g] - mrow);
                p[ct][g] = e;
                psum += e;
            }
        psum += __shfl_xor(psum, 16);
        psum += __shfl_xor(psum, 32);
        lrow = lrow * alpha + psum;
#pragma unroll
        for (int dt = 0; dt < 4; dt++)
#pragma unroll
            for (int g = 0; g < 4; g++) Oacc[dt][g] *= alpha;

        __syncthreads();   // (3) all score-phase LDS reads done before P alias write

        // --- P^T -> PsT (wave-local rows, packed) ---
#pragma unroll
        for (int ct = 0; ct < 4; ct++) {
            *(uint2*)&PsT[l_loc * 72 + ct * 16 + quad * 4] =
                make_uint2(pkbf(p[ct][0], p[ct][1]), pkbf(p[ct][2], p[ct][3]));
        }

        // --- O^T += V^T P^T (no barrier: PsT rows are wave-local) ---
#pragma unroll
        for (int c = 0; c < 2; c++) {
            short8 pb = *(const short8*)&PsT[l_loc * 72 + c * 32 + quad * 8];
#pragma unroll
            for (int dt = 0; dt < 4; dt++) {
                const ushort_t* vp = vth + (size_t)(dt * 16 + lq) * SS
                                         + r0 + c * 32 + quad * 8;
                short8 va = *(const short8*)vp;
                Oacc[dt] = MFMA_16x16x32(va, pb, Oacc[dt]);
            }
        }
    }

    // --- epilogue: ctx[b, l, h*64 + d] bf16, packed over d ---
    const float invl = 1.0f / lrow;
    ushort_t* cbase = ctx + (size_t)(b * SS + l0 + w * 16 + lq) * HH + h * DD;
#pragma unroll
    for (int dt = 0; dt < 4; dt++) {
        *(uint2*)(cbase + dt * 16 + quad * 4) =
            make_uint2(pkbf(Oacc[dt][0] * invl, Oacc[dt][1] * invl),
                       pkbf(Oacc[dt][2] * invl, Oacc[dt][3] * invl));
    }
}

// ---------------------------------------------------------------------------
// Kernel 3: output projection, MFMA, swapped operands (C^T layout) so the
// epilogue does float4 stores.  y = ctx @ Wo^T + bo + x  (fp32 out).
// grid (16, 32), block 256 (4 waves, 2x2 of 64x32).
// ---------------------------------------------------------------------------
__global__ __launch_bounds__(256)
void out_proj(const ushort_t* __restrict__ ctx, const ushort_t* __restrict__ Wob,
              const float* __restrict__ bo, const float* __restrict__ x,
              float* __restrict__ y)
{
    const int tid = threadIdx.x, w = tid >> 6, lane = tid & 63;
    const int quad = lane >> 4, lq = lane & 15;
    const int wm = w >> 1, wn = w & 1;
    const int m0 = blockIdx.y * 128 + wm * 64;
    const int n0 = blockIdx.x * 64 + wn * 32;

    f32x4 acc[4][2];
#pragma unroll
    for (int i = 0; i < 4; i++)
#pragma unroll
        for (int j = 0; j < 2; j++) acc[i][j] = (f32x4){0.f, 0.f, 0.f, 0.f};

    const ushort_t* aB = ctx + (size_t)(m0 + lq) * 1024 + quad * 8;
    const ushort_t* bB = Wob + (size_t)(n0 + lq) * 1024 + quad * 8;

#pragma unroll 2
    for (int k0 = 0; k0 < 1024; k0 += 32) {
        short8 af[4], bf[2];
#pragma unroll
        for (int i = 0; i < 4; i++) af[i] = *(const short8*)(aB + i * 16 * 1024 + k0);
#pragma unroll
        for (int j = 0; j < 2; j++) bf[j] = *(const short8*)(bB + j * 16 * 1024 + k0);
#pragma unroll
        for (int i = 0; i < 4; i++)
#pragma unroll
            for (int j = 0; j < 2; j++)
                acc[i][j] = MFMA_16x16x32(bf[j], af[i], acc[i][j]);
    }

#pragma unroll
    for (int j = 0; j < 2; j++) {
        const int nn = n0 + j * 16 + quad * 4;
        const float4 b4 = *(const float4*)(bo + nn);
#pragma unroll
        for (int i = 0; i < 4; i++) {
            const int m = m0 + i * 16 + lq;
            const float4 x4 = *(const float4*)(x + (size_t)m * 1024 + nn);
            float4 o;
            o.x = acc[i][j][0] + b4.x + x4.x;
            o.y = acc[i][j][1] + b4.y + x4.y;
            o.z = acc[i][j][2] + b4.z + x4.z;
            o.w = acc[i][j][3] + b4.w + x4.w;
            *(float4*)(y + (size_t)m * 1024 + nn) = o;
        }
    }
}

// ---------------------------------------------------------------------------
// Kernel 4: LayerNorm per row (float4), fp32 out.  grid 4096, block 256.
// ---------------------------------------------------------------------------
__global__ void layernorm(const float* __restrict__ y, const float* __restrict__ g,
                          const float* __restrict__ beta, float* __restrict__ out)
{
    const int row = blockIdx.x;
    const int tid = threadIdx.x;

    __shared__ float red[256];
    __shared__ float red2[256];

    const float4 t4 = *(const float4*)(y + (size_t)row * 1024 + tid * 4);
    float s  = t4.x + t4.y + t4.z + t4.w;
    float s2 = t4.x * t4.x + t4.y * t4.y + t4.z * t4.z + t4.w * t4.w;
    red[tid] = s;
    red2[tid] = s2;
    __syncthreads();
    for (int st = 128; st > 0; st >>= 1) {
        if (tid < st) { red[tid] += red[tid + st]; red2[tid] += red2[tid + st]; }
        __syncthreads();
    }
    const float mu  = red[0] * (1.0f / 1024.0f);
    const float var = red2[0] * (1.0f / 1024.0f) - mu * mu;
    const float rs  = rsqrtf(var + 1e-12f);

    const float4 g4 = *(const float4*)(g + tid * 4);
    const float4 b4 = *(const float4*)(beta + tid * 4);
    float4 o;
    o.x = (t4.x - mu) * rs * g4.x + b4.x;
    o.y = (t4.y - mu) * rs * g4.y + b4.y;
    o.z = (t4.z - mu) * rs * g4.z + b4.z;
    o.w = (t4.w - mu) * rs * g4.w + b4.w;
    *(float4*)(out + (size_t)row * 1024 + tid * 4) = o;
}

// ---------------------------------------------------------------------------
extern "C" void kernel_launch(void* const* d_in, const int* in_sizes, int n_in,
                              void* d_out, int out_size, void* d_ws, size_t ws_size,
                              hipStream_t stream)
{
    const float* x    = (const float*)d_in[0];
    const float* mask = (const float*)d_in[1];
    const float* Wq   = (const float*)d_in[2];
    const float* bq   = (const float*)d_in[3];
    const float* Wk   = (const float*)d_in[4];
    const float* bk   = (const float*)d_in[5];
    const float* Wv   = (const float*)d_in[6];
    const float* bv   = (const float*)d_in[7];
    const float* dist = (const float*)d_in[8];
    const float* Wo   = (const float*)d_in[9];
    const float* bo   = (const float*)d_in[10];
    const float* g    = (const float*)d_in[11];
    const float* be   = (const float*)d_in[12];

    // ws bytes (40.25 MB, <= 44 MB proven-safe):
    //  xb [0,8M) | Wqb [8,10M) Wkb [10,12M) Wvb [12,14M) Wob [14,16M)
    //  qb [16,24M) kb [24,32M) vt [32,40M) (V^T [B,NH,D,S]) | Eb [40,40.25M)
    //  y fp32 overlays [16,32M) (qb/kb dead after attn)
    // d_out scratch: ctx bf16 until layernorm overwrites fp32.
    char* wsb = (char*)d_ws;
    ushort_t* xb  = (ushort_t*)(wsb);
    ushort_t* Wqb = (ushort_t*)(wsb + ( 8u << 20));
    ushort_t* Wkb = (ushort_t*)(wsb + (10u << 20));
    ushort_t* Wvb = (ushort_t*)(wsb + (12u << 20));
    ushort_t* Wob = (ushort_t*)(wsb + (14u << 20));
    ushort_t* qbu = (ushort_t*)(wsb + (16u << 20));
    ushort_t* kbu = (ushort_t*)(wsb + (24u << 20));
    ushort_t* vtb = (ushort_t*)(wsb + (32u << 20));
    ushort_t* Eb  = (ushort_t*)(wsb + (40u << 20));
    float*    y   = (float*)(wsb + (16u << 20));
    ushort_t* ctxb = (ushort_t*)d_out;

    conv_all<<<8320, 256, 0, stream>>>(x, Wq, Wk, Wv, Wo, dist,
                                       xb, Wqb, Wkb, Wvb, Wob, Eb);
    qkv_mfma<<<dim3(8, 32, 3), 256, 0, stream>>>(xb, Wqb, bq, Wkb, bk, Wvb, bv,
                                                 qbu, kbu, vtb);
    attn_mfma<<<dim3(16, 16, 4), 256, 0, stream>>>(qbu, kbu, vtb, Eb, mask, ctxb);
    out_proj<<<dim3(16, 32), 256, 0, stream>>>(ctxb, Wob, bo, x, y);
    layernorm<<<4096, 256, 0, stream>>>(y, g, be, (float*)d_out);
}

// Round 10
// 531.295 us; speedup vs baseline: 1.1793x; 1.1793x over previous
//
#include <hip/hip_runtime.h>
#include <hip/hip_bf16.h>

#define BB 4
#define SS 1024
#define HH 1024
#define NHH 16
#define DD 64
#define MAXPOS 1024

typedef __hip_bfloat16 bf16;
typedef unsigned short ushort_t;
typedef __attribute__((ext_vector_type(8))) short short8;
typedef __attribute__((ext_vector_type(4))) float f32x4;
typedef __attribute__((ext_vector_type(4))) unsigned short us4;

#define MFMA_16x16x32(a, b, c) __builtin_amdgcn_mfma_f32_16x16x32_bf16((a), (b), (c), 0, 0, 0)

__device__ __forceinline__ float bu2f(ushort_t u) {
    union { unsigned int i; float f; } c; c.i = ((unsigned int)u) << 16; return c.f;
}
__device__ __forceinline__ ushort_t f2bu(float f) {
    __hip_bfloat16 h = __float2bfloat16(f);
    return *reinterpret_cast<ushort_t*>(&h);
}
// packed 2xfp32 -> 2xbf16 (v_cvt_pk_bf16_f32), low half = first arg
__device__ __forceinline__ unsigned int pkbf(float a, float b) {
    __hip_bfloat162 h = __float22bfloat162_rn(make_float2(a, b));
    union { __hip_bfloat162 h2; unsigned int u; } c; c.h2 = h;
    return c.u;
}

// ---------------------------------------------------------------------------
// Kernel 0: all fp32->bf16 conversions in one launch (x, 4 weights, E).
// ---------------------------------------------------------------------------
__global__ void conv_all(const float* __restrict__ x,  const float* __restrict__ Wq,
                         const float* __restrict__ Wk, const float* __restrict__ Wv,
                         const float* __restrict__ Wo, const float* __restrict__ dist,
                         ushort_t* __restrict__ xb,  ushort_t* __restrict__ Wqb,
                         ushort_t* __restrict__ Wkb, ushort_t* __restrict__ Wvb,
                         ushort_t* __restrict__ Wob, ushort_t* __restrict__ Eb)
{
    const int i = blockIdx.x * 256 + threadIdx.x;
    const float* src; ushort_t* dst; int off;
    if (i < 1048576)      { src = x;  dst = xb;  off = i; }
    else if (i < 1310720) { src = Wq; dst = Wqb; off = i - 1048576; }
    else if (i < 1572864) { src = Wk; dst = Wkb; off = i - 1310720; }
    else if (i < 1835008) { src = Wv; dst = Wvb; off = i - 1572864; }
    else if (i < 2097152) { src = Wo; dst = Wob; off = i - 1835008; }
    else if (i < 2129920) {
        const int j = i - 2097152;
        float4 f = (j < 32752) ? ((const float4*)dist)[j] : make_float4(0.f, 0.f, 0.f, 0.f);
        ((uint2*)Eb)[j] = make_uint2(pkbf(f.x, f.y), pkbf(f.z, f.w));
        return;
    } else return;
    float4 f = ((const float4*)src)[off];
    ((uint2*)dst)[off] = make_uint2(pkbf(f.x, f.y), pkbf(f.z, f.w));
}

// ---------------------------------------------------------------------------
// Kernel 1: QKV projection, MFMA.  C = xb @ W^T (+bias).
//   Q -> [B,NH,S,D] pre-scaled 0.125;  K -> [B,NH,S,D];  V -> [B,NH,D,S].
// Q/K use SWAPPED MFMA operands (C^T layout) -> packed uint2 stores along d.
// V uses original order (g runs along l) -> packed stores into [d][s].
// grid (8, 32, 3), block 256 (4 waves, 2x2 of 64x64).
// ---------------------------------------------------------------------------
__global__ __launch_bounds__(256)
void qkv_mfma(const ushort_t* __restrict__ xb,
              const ushort_t* __restrict__ Wqb, const float* __restrict__ bq,
              const ushort_t* __restrict__ Wkb, const float* __restrict__ bk,
              const ushort_t* __restrict__ Wvb, const float* __restrict__ bv,
              ushort_t* __restrict__ q, ushort_t* __restrict__ k,
              ushort_t* __restrict__ vt)
{
    const int which = blockIdx.z;
    const ushort_t* __restrict__ W    = (which == 0) ? Wqb : (which == 1) ? Wkb : Wvb;
    const float*    __restrict__ bias = (which == 0) ? bq  : (which == 1) ? bk  : bv;

    const int tid = threadIdx.x, w = tid >> 6, lane = tid & 63;
    const int quad = lane >> 4, lq = lane & 15;
    const int wm = w >> 1, wn = w & 1;
    const int m0 = blockIdx.y * 128 + wm * 64;
    const int n0 = blockIdx.x * 128 + wn * 64;

    f32x4 acc[4][4];
#pragma unroll
    for (int i = 0; i < 4; i++)
#pragma unroll
        for (int j = 0; j < 4; j++) acc[i][j] = (f32x4){0.f, 0.f, 0.f, 0.f};

    const ushort_t* aB = xb + (size_t)(m0 + lq) * 1024 + quad * 8;
    const ushort_t* bB = W  + (size_t)(n0 + lq) * 1024 + quad * 8;

    if (which == 2) {
#pragma unroll 2
        for (int k0 = 0; k0 < 1024; k0 += 32) {
            short8 af[4], bf[4];
#pragma unroll
            for (int i = 0; i < 4; i++) af[i] = *(const short8*)(aB + i * 16 * 1024 + k0);
#pragma unroll
            for (int j = 0; j < 4; j++) bf[j] = *(const short8*)(bB + j * 16 * 1024 + k0);
#pragma unroll
            for (int i = 0; i < 4; i++)
#pragma unroll
                for (int j = 0; j < 4; j++)
                    acc[i][j] = MFMA_16x16x32(af[i], bf[j], acc[i][j]);
        }
        // V^T epilogue: lane holds (m = quad*4+g contiguous l, n = lq -> d)
#pragma unroll
        for (int j = 0; j < 4; j++) {
            const int n  = n0 + j * 16 + lq;
            const int h_ = n >> 6, d_ = n & 63;
            const float bb = bias[n];
#pragma unroll
            for (int i = 0; i < 4; i++) {
                const int m  = m0 + i * 16 + quad * 4;
                const int b_ = m >> 10, l = m & 1023;
                uint2 pv = make_uint2(pkbf(acc[i][j][0] + bb, acc[i][j][1] + bb),
                                      pkbf(acc[i][j][2] + bb, acc[i][j][3] + bb));
                *(uint2*)(vt + (((size_t)(b_ * NHH) + h_) * DD + d_) * SS + l) = pv;
            }
        }
    } else {
        // swapped operands: C^T layout, lane holds (n = quad*4+g -> d, m = lq -> l)
#pragma unroll 2
        for (int k0 = 0; k0 < 1024; k0 += 32) {
            short8 af[4], bf[4];
#pragma unroll
            for (int i = 0; i < 4; i++) af[i] = *(const short8*)(aB + i * 16 * 1024 + k0);
#pragma unroll
            for (int j = 0; j < 4; j++) bf[j] = *(const short8*)(bB + j * 16 * 1024 + k0);
#pragma unroll
            for (int i = 0; i < 4; i++)
#pragma unroll
                for (int j = 0; j < 4; j++)
                    acc[i][j] = MFMA_16x16x32(bf[j], af[i], acc[i][j]);
        }
        ushort_t* __restrict__ out = (which == 0) ? q : k;
        const float sc = (which == 0) ? 0.125f : 1.0f;
#pragma unroll
        for (int j = 0; j < 4; j++) {
            const int nn = n0 + j * 16 + quad * 4;   // g=0 col
            const int h_ = nn >> 6, d0 = nn & 63;
            float bs[4];
#pragma unroll
            for (int g = 0; g < 4; g++) bs[g] = bias[nn + g];
#pragma unroll
            for (int i = 0; i < 4; i++) {
                const int m  = m0 + i * 16 + lq;
                const int b_ = m >> 10, l = m & 1023;
                float s0 = (acc[i][j][0] + bs[0]) * sc;
                float s1 = (acc[i][j][1] + bs[1]) * sc;
                float s2 = (acc[i][j][2] + bs[2]) * sc;
                float s3 = (acc[i][j][3] + bs[3]) * sc;
                *(uint2*)(out + (((size_t)(b_ * NHH) + h_) * SS + l) * DD + d0) =
                    make_uint2(pkbf(s0, s1), pkbf(s2, s3));
            }
        }
    }
}

// ---------------------------------------------------------------------------
// Kernel 2: MFMA flash attention, S^T formulation.
// LDS = QEsT + KEsT only (34,816 B); PsT aliases the head of QEsT behind a
// 3rd barrier.  4 wg/CU requires VGPR<=128: the natural allocation is 128
// (R8 measured) — do NOT force min-waves via launch_bounds, it spills
// (R9: VGPR 64, +380MB scratch traffic, 1.7x slower).
// grid (16, 16, 4), block 256.
// ---------------------------------------------------------------------------
__global__ __launch_bounds__(256)
void attn_mfma(const ushort_t* __restrict__ qb, const ushort_t* __restrict__ kb,
               const ushort_t* __restrict__ vt, const ushort_t* __restrict__ Eb,
               const float* __restrict__ mask, ushort_t* __restrict__ ctx)
{
    const int l0 = blockIdx.x * 64;
    const int h  = blockIdx.y, b = blockIdx.z;
    const int tid  = threadIdx.x;
    const int w    = tid >> 6;
    const int lane = tid & 63;
    const int quad = lane >> 4, lq = lane & 15;

    __shared__ __align__(16) ushort_t QEsT[128 * 68];   // [t][l]
    __shared__ __align__(16) ushort_t KEsT[128 * 68];   // [t][r]
    ushort_t* const PsT = QEsT;                         // [l][r] stride 72, alias

    const ushort_t* qbh = qb + (size_t)(b * NHH + h) * SS * DD;
    const ushort_t* kbh = kb + (size_t)(b * NHH + h) * SS * DD;
    const ushort_t* vth = vt + (size_t)(b * NHH + h) * DD * SS;   // [d][s]

    short8 qa0, qa1;
    {
        const ushort_t* p = qbh + (l0 + w * 16 + lq) * DD + quad * 8;
        qa0 = *(const short8*)p;
        qa1 = *(const short8*)(p + 32);
    }
    const int l_loc = w * 16 + lq;

    f32x4 Oacc[4];
#pragma unroll
    for (int dt = 0; dt < 4; dt++) Oacc[dt] = (f32x4){0.f, 0.f, 0.f, 0.f};
    float mrow = -3e38f, lrow = 0.f;

    for (int rt = 0; rt < 16; rt++) {
        const int r0   = rt * 64;
        const int dmin = l0 - r0 + 960;

        short8 kf0[4], kf1[4];
#pragma unroll
        for (int ct = 0; ct < 4; ct++) {
            const ushort_t* p = kbh + (r0 + ct * 16 + lq) * DD + quad * 8;
            kf0[ct] = *(const short8*)p;
            kf1[ct] = *(const short8*)(p + 32);
        }
        float mk[4];
#pragma unroll
        for (int g = 0; g < 4; g++) mk[g] = mask[b * SS + r0 + w * 16 + quad * 4 + g];

        __syncthreads();   // (1) prior tile: score reads + PV reads of PsT alias done

        // --- QE / KE' via MFMA, transposed packed stores ---
#pragma unroll
        for (int tt = 0; tt < 8; tt++) {
            const ushort_t* ep = Eb + (size_t)(dmin + tt * 16 + lq) * DD + quad * 8;
            short8 e0 = *(const short8*)ep;
            short8 e1 = *(const short8*)(ep + 32);
            f32x4 qe = (f32x4){0.f, 0.f, 0.f, 0.f};
            f32x4 ke = (f32x4){0.f, 0.f, 0.f, 0.f};
            qe = MFMA_16x16x32(qa0, e0, qe);
            qe = MFMA_16x16x32(qa1, e1, qe);
            ke = MFMA_16x16x32(kf0[w], e0, ke);
            ke = MFMA_16x16x32(kf1[w], e1, ke);
            const float k0 = ke[0] * 0.125f + mk[0];
            const float k1 = ke[1] * 0.125f + mk[1];
            const float k2 = ke[2] * 0.125f + mk[2];
            const float k3 = ke[3] * 0.125f + mk[3];
            const int trow = tt * 16 + lq;
            *(uint2*)&QEsT[trow * 68 + w * 16 + quad * 4] =
                make_uint2(pkbf(qe[0], qe[1]), pkbf(qe[2], qe[3]));
            *(uint2*)&KEsT[trow * 68 + w * 16 + quad * 4] =
                make_uint2(pkbf(k0, k1), pkbf(k2, k3));
        }

        // --- S^T = K Q^T for this wave's l-block ---
        f32x4 st[4];
#pragma unroll
        for (int ct = 0; ct < 4; ct++) {
            f32x4 a = (f32x4){0.f, 0.f, 0.f, 0.f};
            a = MFMA_16x16x32(kf0[ct], qa0, a);
            a = MFMA_16x16x32(kf1[ct], qa1, a);
            st[ct] = a;
        }

        __syncthreads();   // (2) QEsT/KEsT visible

        // --- scores + online softmax (per-lane l fixed) ---
        float p[4][4];
        float tmax = -3e38f;
#pragma unroll
        for (int ct = 0; ct < 4; ct++) {
#pragma unroll
            for (int g = 0; g < 4; g++) {
                const int r_loc = ct * 16 + quad * 4 + g;
                const int t = l_loc - r_loc + 63;      // [0,126]
                float s = st[ct][g] + bu2f(QEsT[t * 68 + l_loc])
                                    + bu2f(KEsT[t * 68 + r_loc]);
                p[ct][g] = s;
                tmax = fmaxf(tmax, s);
            }
        }
        tmax = fmaxf(tmax, __shfl_xor(tmax, 16));
        tmax = fmaxf(tmax, __shfl_xor(tmax, 32));
        const float mnew  = fmaxf(mrow, tmax);
        const float alpha = __expf(mrow - mnew);
        mrow = mnew;
        float psum = 0.f;
#pragma unroll
        for (int ct = 0; ct < 4; ct++)
#pragma unroll
            for (int g = 0; g < 4; g++) {
                const float e = __expf(p[ct][g] - mrow);
                p[ct][g] = e;
                psum += e;
            }
        psum += __shfl_xor(psum, 16);
        psum += __shfl_xor(psum, 32);
        lrow = lrow * alpha + psum;
#pragma unroll
        for (int dt = 0; dt < 4; dt++)
#pragma unroll
            for (int g = 0; g < 4; g++) Oacc[dt][g] *= alpha;

        __syncthreads();   // (3) all score-phase LDS reads done before P alias write

        // --- P^T -> PsT (wave-local rows, packed) ---
#pragma unroll
        for (int ct = 0; ct < 4; ct++) {
            *(uint2*)&PsT[l_loc * 72 + ct * 16 + quad * 4] =
                make_uint2(pkbf(p[ct][0], p[ct][1]), pkbf(p[ct][2], p[ct][3]));
        }

        // --- O^T += V^T P^T (no barrier: PsT rows are wave-local) ---
#pragma unroll
        for (int c = 0; c < 2; c++) {
            short8 pb = *(const short8*)&PsT[l_loc * 72 + c * 32 + quad * 8];
#pragma unroll
            for (int dt = 0; dt < 4; dt++) {
                const ushort_t* vp = vth + (size_t)(dt * 16 + lq) * SS
                                         + r0 + c * 32 + quad * 8;
                short8 va = *(const short8*)vp;
                Oacc[dt] = MFMA_16x16x32(va, pb, Oacc[dt]);
            }
        }
    }

    // --- epilogue: ctx[b, l, h*64 + d] bf16, packed over d ---
    const float invl = 1.0f / lrow;
    ushort_t* cbase = ctx + (size_t)(b * SS + l0 + w * 16 + lq) * HH + h * DD;
#pragma unroll
    for (int dt = 0; dt < 4; dt++) {
        *(uint2*)(cbase + dt * 16 + quad * 4) =
            make_uint2(pkbf(Oacc[dt][0] * invl, Oacc[dt][1] * invl),
                       pkbf(Oacc[dt][2] * invl, Oacc[dt][3] * invl));
    }
}

// ---------------------------------------------------------------------------
// Kernel 3: output projection, MFMA, swapped operands (C^T layout) so the
// epilogue does float4 stores.  y = ctx @ Wo^T + bo + x  (fp32 out).
// grid (16, 32), block 256 (4 waves, 2x2 of 64x32).
// ---------------------------------------------------------------------------
__global__ __launch_bounds__(256)
void out_proj(const ushort_t* __restrict__ ctx, const ushort_t* __restrict__ Wob,
              const float* __restrict__ bo, const float* __restrict__ x,
              float* __restrict__ y)
{
    const int tid = threadIdx.x, w = tid >> 6, lane = tid & 63;
    const int quad = lane >> 4, lq = lane & 15;
    const int wm = w >> 1, wn = w & 1;
    const int m0 = blockIdx.y * 128 + wm * 64;
    const int n0 = blockIdx.x * 64 + wn * 32;

    f32x4 acc[4][2];
#pragma unroll
    for (int i = 0; i < 4; i++)
#pragma unroll
        for (int j = 0; j < 2; j++) acc[i][j] = (f32x4){0.f, 0.f, 0.f, 0.f};

    const ushort_t* aB = ctx + (size_t)(m0 + lq) * 1024 + quad * 8;
    const ushort_t* bB = Wob + (size_t)(n0 + lq) * 1024 + quad * 8;

#pragma unroll 2
    for (int k0 = 0; k0 < 1024; k0 += 32) {
        short8 af[4], bf[2];
#pragma unroll
        for (int i = 0; i < 4; i++) af[i] = *(const short8*)(aB + i * 16 * 1024 + k0);
#pragma unroll
        for (int j = 0; j < 2; j++) bf[j] = *(const short8*)(bB + j * 16 * 1024 + k0);
#pragma unroll
        for (int i = 0; i < 4; i++)
#pragma unroll
            for (int j = 0; j < 2; j++)
                acc[i][j] = MFMA_16x16x32(bf[j], af[i], acc[i][j]);
    }

#pragma unroll
    for (int j = 0; j < 2; j++) {
        const int nn = n0 + j * 16 + quad * 4;
        const float4 b4 = *(const float4*)(bo + nn);
#pragma unroll
        for (int i = 0; i < 4; i++) {
            const int m = m0 + i * 16 + lq;
            const float4 x4 = *(const float4*)(x + (size_t)m * 1024 + nn);
            float4 o;
            o.x = acc[i][j][0] + b4.x + x4.x;
            o.y = acc[i][j][1] + b4.y + x4.y;
            o.z = acc[i][j][2] + b4.z + x4.z;
            o.w = acc[i][j][3] + b4.w + x4.w;
            *(float4*)(y + (size_t)m * 1024 + nn) = o;
        }
    }
}

// ---------------------------------------------------------------------------
// Kernel 4: LayerNorm per row (float4), fp32 out.  grid 4096, block 256.
// ---------------------------------------------------------------------------
__global__ void layernorm(const float* __restrict__ y, const float* __restrict__ g,
                          const float* __restrict__ beta, float* __restrict__ out)
{
    const int row = blockIdx.x;
    const int tid = threadIdx.x;

    __shared__ float red[256];
    __shared__ float red2[256];

    const float4 t4 = *(const float4*)(y + (size_t)row * 1024 + tid * 4);
    float s  = t4.x + t4.y + t4.z + t4.w;
    float s2 = t4.x * t4.x + t4.y * t4.y + t4.z * t4.z + t4.w * t4.w;
    red[tid] = s;
    red2[tid] = s2;
    __syncthreads();
    for (int st = 128; st > 0; st >>= 1) {
        if (tid < st) { red[tid] += red[tid + st]; red2[tid] += red2[tid + st]; }
        __syncthreads();
    }
    const float mu  = red[0] * (1.0f / 1024.0f);
    const float var = red2[0] * (1.0f / 1024.0f) - mu * mu;
    const float rs  = rsqrtf(var + 1e-12f);

    const float4 g4 = *(const float4*)(g + tid * 4);
    const float4 b4 = *(const float4*)(beta + tid * 4);
    float4 o;
    o.x = (t4.x - mu) * rs * g4.x + b4.x;
    o.y = (t4.y - mu) * rs * g4.y + b4.y;
    o.z = (t4.z - mu) * rs * g4.z + b4.z;
    o.w = (t4.w - mu) * rs * g4.w + b4.w;
    *(float4*)(out + (size_t)row * 1024 + tid * 4) = o;
}

// ---------------------------------------------------------------------------
extern "C" void kernel_launch(void* const* d_in, const int* in_sizes, int n_in,
                              void* d_out, int out_size, void* d_ws, size_t ws_size,
                              hipStream_t stream)
{
    const float* x    = (const float*)d_in[0];
    const float* mask = (const float*)d_in[1];
    const float* Wq   = (const float*)d_in[2];
    const float* bq   = (const float*)d_in[3];
    const float* Wk   = (const float*)d_in[4];
    const float* bk   = (const float*)d_in[5];
    const float* Wv   = (const float*)d_in[6];
    const float* bv   = (const float*)d_in[7];
    const float* dist = (const float*)d_in[8];
    const float* Wo   = (const float*)d_in[9];
    const float* bo   = (const float*)d_in[10];
    const float* g    = (const float*)d_in[11];
    const float* be   = (const float*)d_in[12];

    // ws bytes (40.25 MB, <= 44 MB proven-safe):
    //  xb [0,8M) | Wqb [8,10M) Wkb [10,12M) Wvb [12,14M) Wob [14,16M)
    //  qb [16,24M) kb [24,32M) vt [32,40M) (V^T [B,NH,D,S]) | Eb [40,40.25M)
    //  y fp32 overlays [16,32M) (qb/kb dead after attn)
    // d_out scratch: ctx bf16 until layernorm overwrites fp32.
    char* wsb = (char*)d_ws;
    ushort_t* xb  = (ushort_t*)(wsb);
    ushort_t* Wqb = (ushort_t*)(wsb + ( 8u << 20));
    ushort_t* Wkb = (ushort_t*)(wsb + (10u << 20));
    ushort_t* Wvb = (ushort_t*)(wsb + (12u << 20));
    ushort_t* Wob = (ushort_t*)(wsb + (14u << 20));
    ushort_t* qbu = (ushort_t*)(wsb + (16u << 20));
    ushort_t* kbu = (ushort_t*)(wsb + (24u << 20));
    ushort_t* vtb = (ushort_t*)(wsb + (32u << 20));
    ushort_t* Eb  = (ushort_t*)(wsb + (40u << 20));
    float*    y   = (float*)(wsb + (16u << 20));
    ushort_t* ctxb = (ushort_t*)d_out;

    conv_all<<<8320, 256, 0, stream>>>(x, Wq, Wk, Wv, Wo, dist,
                                       xb, Wqb, Wkb, Wvb, Wob, Eb);
    qkv_mfma<<<dim3(8, 32, 3), 256, 0, stream>>>(xb, Wqb, bq, Wkb, bk, Wvb, bv,
                                                 qbu, kbu, vtb);
    attn_mfma<<<dim3(16, 16, 4), 256, 0, stream>>>(qbu, kbu, vtb, Eb, mask, ctxb);
    out_proj<<<dim3(16, 32), 256, 0, stream>>>(ctxb, Wob, bo, x, y);
    layernorm<<<4096, 256, 0, stream>>>(y, g, be, (float*)d_out);
}